// Round 2
// baseline (3396.183 us; speedup 1.0000x reference)
//
#include <hip/hip_runtime.h>

#define H 1024
#define T_STEPS 64
#define S_MEM 512
#define VA 30
#define VW 30000

__device__ __forceinline__ float sigmf(float x) { return 1.f / (1.f + expf(-x)); }

// ---------------- init: gather embeddings, stack slices, zero states + sync ----------------
__global__ __launch_bounds__(256) void k_init(
    const int* __restrict__ actions, const int* __restrict__ words,
    const float* __restrict__ act_emb, const float* __restrict__ word_emb,
    float* __restrict__ X_term, float* __restrict__ X_act,
    float* __restrict__ fin, int* __restrict__ sync) {
  int b = blockIdx.x, tid = threadIdx.x;
  if (b < T_STEPS) {
    int wi = words[b], ai = actions[b];
    for (int i = tid; i < H; i += 256) {
      float we = word_emb[(size_t)wi * H + i];
      X_term[b * H + i] = we;
      X_act[b * H + i]  = act_emb[(size_t)ai * H + i];
      if (b + 1 < T_STEPS) fin[(size_t)(b + 1) * 4096 + 2048 + i] = we;  // stack_h[t+1]=w_e[t]
    }
    if (b == 0)
      for (int i = tid; i < H; i += 256) fin[2048 + i] = 0.f;            // stack_h[0]=0
  } else {
    for (int i = tid; i < H; i += 256) { fin[i] = 0.f; fin[H + i] = 0.f; }
    if (tid < 64) sync[tid] = 0;
  }
}

// ---------------- fp32 GEMM: C[64,N] = A[64,K] * op(B), 64x64 tile, 4x4 micro ----------------
// BT=true : B row-major [N][K] (C = A*B^T).  BT=false: B row-major [K][N] (C = A*B).
// splitk = gridDim.y. splitk>1 -> partials P[ks][64][N]; ==1 -> direct epilogue.
// LDS tiles stored [64 k][64 slots] with quad swizzle c' = c ^ (k>>2)  (conflict-free b128).
template<bool BT>
__global__ __launch_bounds__(256) void k_gemm64(
    const float* __restrict__ A, int lda,
    const float* __restrict__ B, int ldb,
    int N, int K,
    float* __restrict__ Ppart,
    const float* __restrict__ bias, const float* __restrict__ bias2, int relu,
    float* __restrict__ Cfinal, int ldc) {
  __shared__ __align__(16) float As[64 * 64];
  __shared__ __align__(16) float Bs[64 * 64];
  const float4* As4 = (const float4*)As;
  const float4* Bs4 = (const float4*)Bs;
  int tid = threadIdx.x;
  int cidx = tid & 15;       // cols cidx*4..+3
  int ridx = tid >> 4;       // rows ridx*4..+3
  int n0 = blockIdx.x * 64;
  int splitk = gridDim.y;
  int klen = K / splitk;
  int kbeg = blockIdx.y * klen;
  float acc[4][4] = {};

  for (int k0 = kbeg; k0 < kbeg + klen; k0 += 64) {
    // stage A (transpose to [k][row], swizzled)
#pragma unroll
    for (int i = 0; i < 4; ++i) {
      int f = tid + i * 256;
      int rr = f >> 4, km = f & 15;
      float4 v = *(const float4*)&A[(size_t)rr * lda + k0 + km * 4];
      int c2 = ((rr >> 2) ^ km) & 15, p = rr & 3;
      As[(km * 4 + 0) * 64 + c2 * 4 + p] = v.x;
      As[(km * 4 + 1) * 64 + c2 * 4 + p] = v.y;
      As[(km * 4 + 2) * 64 + c2 * 4 + p] = v.z;
      As[(km * 4 + 3) * 64 + c2 * 4 + p] = v.w;
    }
    if (BT) {
#pragma unroll
      for (int i = 0; i < 4; ++i) {
        int f = tid + i * 256;
        int nn = f >> 4, km = f & 15;
        int gn = n0 + nn;
        float4 v = make_float4(0.f, 0.f, 0.f, 0.f);
        if (gn < N) v = *(const float4*)&B[(size_t)gn * ldb + k0 + km * 4];
        int c2 = ((nn >> 2) ^ km) & 15, p = nn & 3;
        Bs[(km * 4 + 0) * 64 + c2 * 4 + p] = v.x;
        Bs[(km * 4 + 1) * 64 + c2 * 4 + p] = v.y;
        Bs[(km * 4 + 2) * 64 + c2 * 4 + p] = v.z;
        Bs[(km * 4 + 3) * 64 + c2 * 4 + p] = v.w;
      }
    } else {
#pragma unroll
      for (int i = 0; i < 4; ++i) {
        int f = tid + i * 256;
        int kr = f >> 4, nq = f & 15;
        int gn = n0 + nq * 4;
        float4 v = make_float4(0.f, 0.f, 0.f, 0.f);
        if (gn < N) v = *(const float4*)&B[(size_t)(k0 + kr) * ldb + gn];
        ((float4*)Bs)[kr * 16 + ((nq ^ (kr >> 2)) & 15)] = v;
      }
    }
    __syncthreads();
#pragma unroll 8
    for (int kk = 0; kk < 64; ++kk) {
      int sw = kk >> 2;
      float4 a4 = As4[kk * 16 + ((ridx ^ sw) & 15)];
      float4 b4 = Bs4[kk * 16 + ((cidx ^ sw) & 15)];
      float av[4] = {a4.x, a4.y, a4.z, a4.w};
      float bv[4] = {b4.x, b4.y, b4.z, b4.w};
#pragma unroll
      for (int i = 0; i < 4; ++i)
#pragma unroll
        for (int j = 0; j < 4; ++j) acc[i][j] += av[i] * bv[j];
    }
    __syncthreads();
  }

  int gcol = n0 + cidx * 4;
  if (splitk > 1) {
    float* P = Ppart + (size_t)blockIdx.y * 64 * N;
    if (gcol < N) {
#pragma unroll
      for (int i = 0; i < 4; ++i) {
        int row = ridx * 4 + i;
        *(float4*)&P[(size_t)row * N + gcol] =
            make_float4(acc[i][0], acc[i][1], acc[i][2], acc[i][3]);
      }
    }
  } else {
    if (gcol < N) {
      float4 bs = bias ? *(const float4*)&bias[gcol] : make_float4(0, 0, 0, 0);
      if (bias2) {
        float4 b2 = *(const float4*)&bias2[gcol];
        bs.x += b2.x; bs.y += b2.y; bs.z += b2.z; bs.w += b2.w;
      }
#pragma unroll
      for (int i = 0; i < 4; ++i) {
        int row = ridx * 4 + i;
        float4 v = make_float4(acc[i][0] + bs.x, acc[i][1] + bs.y,
                               acc[i][2] + bs.z, acc[i][3] + bs.w);
        if (relu) {
          v.x = fmaxf(v.x, 0.f); v.y = fmaxf(v.y, 0.f);
          v.z = fmaxf(v.z, 0.f); v.w = fmaxf(v.w, 0.f);
        }
        *(float4*)&Cfinal[(size_t)row * ldc + gcol] = v;
      }
    }
  }
}

// ---------------- split-K reduce + bias(+bias2)(+relu), float4 ----------------
__global__ __launch_bounds__(256) void k_reduce4(
    const float* __restrict__ P, int S, int N,
    const float* __restrict__ bias, const float* __restrict__ bias2, int relu,
    float* __restrict__ out, int ldc) {
  int q = blockIdx.x * 256 + threadIdx.x;       // float4 index
  int total = 64 * N / 4;
  if (q >= total) return;
  int e0 = q * 4;
  int row = e0 / N, col = e0 - row * N;
  float4 v = make_float4(0, 0, 0, 0);
  for (int s = 0; s < S; ++s) {
    float4 p = *(const float4*)&P[(size_t)s * 64 * N + e0];
    v.x += p.x; v.y += p.y; v.z += p.z; v.w += p.w;
  }
  if (bias) {
    float4 b = *(const float4*)&bias[col];
    v.x += b.x; v.y += b.y; v.z += b.z; v.w += b.w;
  }
  if (bias2) {
    float4 b = *(const float4*)&bias2[col];
    v.x += b.x; v.y += b.y; v.z += b.z; v.w += b.w;
  }
  if (relu) {
    v.x = fmaxf(v.x, 0.f); v.y = fmaxf(v.y, 0.f);
    v.z = fmaxf(v.z, 0.f); v.w = fmaxf(v.w, 0.f);
  }
  *(float4*)&out[(size_t)row * ldc + col] = v;
}

// ---------------- persistent recurrence: all 63 steps, custom device barrier ----------------
// 256 WGs x 256 threads. WG owns lstm = wg>>7, h-elems [(wg&127)*8, +8) -> 32 gate rows.
__global__ __launch_bounds__(256) void k_recur(
    const float* __restrict__ Whh_term, const float* __restrict__ Whh_act,
    const float* __restrict__ xg_term, const float* __restrict__ xg_act,
    float* __restrict__ fin, int* __restrict__ sync) {
  __shared__ float hs[1024];
  __shared__ float gs[32];
  __shared__ float cs[8];
  int wg = blockIdx.x;
  int lstm = wg >> 7;
  int k0 = (wg & 127) * 8;
  const float* Whh = lstm ? Whh_act : Whh_term;
  const float* xg  = lstm ? xg_act : xg_term;
  int tid = threadIdx.x;
  if (tid < 8) cs[tid] = 0.f;
  int d = tid >> 3, p = tid & 7;                 // d: 32 gate rows, p: K-eighth
  int gate = d >> 3, e = d & 7;
  int row = gate * 1024 + k0 + e;
  const float* wrow = Whh + (size_t)row * 1024 + p * 128;

  for (int t = 0; t < 63; ++t) {
    const float* hin = fin + (size_t)t * 4096 + lstm * 1024;
    *(float4*)&hs[tid * 4] = *(const float4*)&hin[tid * 4];
    __syncthreads();
    const float* hp = hs + p * 128;
    float sum = 0.f;
#pragma unroll
    for (int i = 0; i < 128; i += 4) {
      float4 wv = *(const float4*)(wrow + i);
      float4 hv = *(const float4*)(hp + i);
      sum += wv.x * hv.x + wv.y * hv.y + wv.z * hv.z + wv.w * hv.w;
    }
    sum += __shfl_xor(sum, 1);
    sum += __shfl_xor(sum, 2);
    sum += __shfl_xor(sum, 4);
    if (p == 0) gs[d] = sum + xg[(size_t)t * 4096 + row];
    __syncthreads();
    if (tid < 8) {
      float gi = gs[tid], gf = gs[8 + tid], gg = gs[16 + tid], go = gs[24 + tid];
      float c = cs[tid];
      float c2 = sigmf(gf) * c + sigmf(gi) * tanhf(gg);
      float h2 = sigmf(go) * tanhf(c2);
      cs[tid] = c2;
      fin[(size_t)(t + 1) * 4096 + lstm * 1024 + k0 + tid] = h2;
    }
    __threadfence();       // make h2 visible (release side)
    __syncthreads();
    if (tid == 0)
      __hip_atomic_fetch_add(&sync[t], 1, __ATOMIC_RELEASE, __HIP_MEMORY_SCOPE_AGENT);
    if (t < 62) {
      if (tid == 0) {
        while (__hip_atomic_load(&sync[t], __ATOMIC_ACQUIRE, __HIP_MEMORY_SCOPE_AGENT) < 256)
          __builtin_amdgcn_s_sleep(2);
      }
      __syncthreads();
      __threadfence();     // acquire side: invalidate L1 before reading fresh h
    }
  }
}

// ---------------- action logits: [64,30] = ha @ Wa2^T + ba2 ----------------
__global__ __launch_bounds__(256) void k_actlog(
    const float* __restrict__ ha, const float* __restrict__ Wa2,
    const float* __restrict__ ba2, float* __restrict__ out) {
  int t = blockIdx.x, tid = threadIdx.x;
  int v = tid >> 3, p = tid & 7;
  float sum = 0.f;
  if (v < VA) {
    const float* a  = ha + (size_t)t * 1024 + p * 128;
    const float* wr = Wa2 + (size_t)v * 1024 + p * 128;
#pragma unroll 8
    for (int i = 0; i < 128; i += 4) {
      float4 av = *(const float4*)(a + i);
      float4 wv = *(const float4*)(wr + i);
      sum += av.x * wv.x + av.y * wv.y + av.z * wv.z + av.w * wv.w;
    }
  }
  sum += __shfl_xor(sum, 1);
  sum += __shfl_xor(sum, 2);
  sum += __shfl_xor(sum, 4);
  if (p == 0 && v < VA) out[(size_t)t * VA + v] = sum + ba2[v];
}

extern "C" void kernel_launch(void* const* d_in, const int* in_sizes, int n_in,
                              void* d_out, int out_size, void* d_ws, size_t ws_size,
                              hipStream_t stream) {
  const float* memory   = (const float*)d_in[0];
  const int*   actions  = (const int*)d_in[1];
  const int*   words    = (const int*)d_in[2];
  const float* term_Wih = (const float*)d_in[3];
  const float* term_Whh = (const float*)d_in[4];
  const float* term_bih = (const float*)d_in[5];
  const float* term_bhh = (const float*)d_in[6];
  const float* act_Wih  = (const float*)d_in[7];
  const float* act_Whh  = (const float*)d_in[8];
  const float* act_bih  = (const float*)d_in[9];
  const float* act_bhh  = (const float*)d_in[10];
  const float* Wq  = (const float*)d_in[11];
  const float* bq  = (const float*)d_in[12];
  const float* Wa1 = (const float*)d_in[13];
  const float* ba1 = (const float*)d_in[14];
  const float* Wa2 = (const float*)d_in[15];
  const float* ba2 = (const float*)d_in[16];
  const float* Ww1 = (const float*)d_in[17];
  const float* bw1 = (const float*)d_in[18];
  const float* Ww2 = (const float*)d_in[19];
  const float* bw2 = (const float*)d_in[20];
  const float* act_emb  = (const float*)d_in[21];
  const float* word_emb = (const float*)d_in[22];
  float* out = (float*)d_out;

  // workspace layout (floats)
  float* w       = (float*)d_ws;
  float* X_term  = w;                   // 64*1024
  float* X_act   = X_term + 65536;
  float* xg_term = X_act + 65536;       // 64*4096
  float* xg_act  = xg_term + 262144;
  float* fin     = xg_act + 262144;     // 64*4096 [term_h|act_h|stack|ctx]
  float* qbuf    = fin + 262144;        // 64*1024
  float* attn    = qbuf + 65536;        // 64*512
  float* ha      = attn + 32768;        // 64*1024
  float* hw      = ha + 65536;          // 64*1024
  int*   sync    = (int*)(hw + 65536);  // 64 ints
  float* P       = (float*)(sync + 64); // partials

  size_t base_fl = (size_t)(P - w);
  int wsplit = (ws_size >= (base_fl + 2ull * 64 * VW + 1024) * 4) ? 2 : 1;

  k_init<<<65, 256, 0, stream>>>(actions, words, act_emb, word_emb,
                                 X_term, X_act, fin, sync);

  // xg = X @ Wih^T + bih + bhh   (N=4096, K=1024, splitk=4)
  k_gemm64<true><<<dim3(64, 4), 256, 0, stream>>>(X_term, 1024, term_Wih, 1024, 4096, 1024,
                                                  P, nullptr, nullptr, 0, nullptr, 0);
  k_reduce4<<<256, 256, 0, stream>>>(P, 4, 4096, term_bih, term_bhh, 0, xg_term, 4096);
  k_gemm64<true><<<dim3(64, 4), 256, 0, stream>>>(X_act, 1024, act_Wih, 1024, 4096, 1024,
                                                  P, nullptr, nullptr, 0, nullptr, 0);
  k_reduce4<<<256, 256, 0, stream>>>(P, 4, 4096, act_bih, act_bhh, 0, xg_act, 4096);

  // all 63 recurrence steps in one persistent kernel
  k_recur<<<256, 256, 0, stream>>>(term_Whh, act_Whh, xg_term, xg_act, fin, sync);

  // q = states @ Wq^T + bq   (K=3072, N=1024, splitk=4)
  k_gemm64<true><<<dim3(16, 4), 256, 0, stream>>>(fin, 4096, Wq, 3072, 1024, 3072,
                                                  P, nullptr, nullptr, 0, nullptr, 0);
  k_reduce4<<<64, 256, 0, stream>>>(P, 4, 1024, bq, nullptr, 0, qbuf, 1024);

  // attn = q . memory   (N=512, K=1024, splitk=2)
  k_gemm64<true><<<dim3(8, 2), 256, 0, stream>>>(qbuf, 1024, memory, 1024, 512, 1024,
                                                 P, nullptr, nullptr, 0, nullptr, 0);
  k_reduce4<<<32, 256, 0, stream>>>(P, 2, 512, nullptr, nullptr, 0, attn, 512);

  // ctx = attn @ memory  (N=1024, K=512, splitk=2) -> fin[:,3072:4096]
  k_gemm64<false><<<dim3(16, 2), 256, 0, stream>>>(attn, 512, memory, 1024, 1024, 512,
                                                   P, nullptr, nullptr, 0, nullptr, 0);
  k_reduce4<<<64, 256, 0, stream>>>(P, 2, 1024, nullptr, nullptr, 0, fin + 3072, 4096);

  // ha = relu(final @ Wa1^T + ba1), hw = relu(final @ Ww1^T + bw1)  (K=4096, splitk=8)
  k_gemm64<true><<<dim3(16, 8), 256, 0, stream>>>(fin, 4096, Wa1, 4096, 1024, 4096,
                                                  P, nullptr, nullptr, 0, nullptr, 0);
  k_reduce4<<<64, 256, 0, stream>>>(P, 8, 1024, ba1, nullptr, 1, ha, 1024);
  k_gemm64<true><<<dim3(16, 8), 256, 0, stream>>>(fin, 4096, Ww1, 4096, 1024, 4096,
                                                  P, nullptr, nullptr, 0, nullptr, 0);
  k_reduce4<<<64, 256, 0, stream>>>(P, 8, 1024, bw1, nullptr, 1, hw, 1024);

  // act_logits -> out[0:1920]
  k_actlog<<<64, 256, 0, stream>>>(ha, Wa2, ba2, out);

  // word_logits = hw @ Ww2^T + bw2 -> out[1920:]
  if (wsplit == 2) {
    k_gemm64<true><<<dim3(469, 2), 256, 0, stream>>>(hw, 1024, Ww2, 1024, VW, 1024,
                                                     P, nullptr, nullptr, 0, nullptr, 0);
    k_reduce4<<<1875, 256, 0, stream>>>(P, 2, VW, bw2, nullptr, 0, out + 1920, VW);
  } else {
    k_gemm64<true><<<dim3(469, 1), 256, 0, stream>>>(hw, 1024, Ww2, 1024, VW, 1024,
                                                     nullptr, bw2, nullptr, 0, out + 1920, VW);
  }
}

// Round 3
// 576.384 us; speedup vs baseline: 5.8922x; 5.8922x over previous
//
#include <hip/hip_runtime.h>

#define H 1024
#define T_STEPS 64
#define S_MEM 512
#define VA 30
#define VW 30000

__device__ __forceinline__ float sigmf(float x) { return 1.f / (1.f + expf(-x)); }

// ---------------- init: gather embeddings, stack slices, zero states + flags ----------------
__global__ __launch_bounds__(256) void k_init(
    const int* __restrict__ actions, const int* __restrict__ words,
    const float* __restrict__ act_emb, const float* __restrict__ word_emb,
    float* __restrict__ X_term, float* __restrict__ X_act,
    float* __restrict__ fin, int* __restrict__ flags) {
  int b = blockIdx.x, tid = threadIdx.x;
  if (b < T_STEPS) {
    int wi = words[b], ai = actions[b];
    for (int i = tid; i < H; i += 256) {
      float we = word_emb[(size_t)wi * H + i];
      X_term[b * H + i] = we;
      X_act[b * H + i]  = act_emb[(size_t)ai * H + i];
      if (b + 1 < T_STEPS) fin[(size_t)(b + 1) * 4096 + 2048 + i] = we;  // stack_h[t+1]=w_e[t]
    }
    if (b == 0)
      for (int i = tid; i < H; i += 256) fin[2048 + i] = 0.f;            // stack_h[0]=0
  } else {
    for (int i = tid; i < H; i += 256) { fin[i] = 0.f; fin[H + i] = 0.f; }
    for (int i = tid; i < 2 * 128 * 16; i += 256) flags[i] = 0;
  }
}

// ---------------- fp32 GEMM: C[64,N] = A[64,K] * op(B), 64x64 tile, 4x4 micro ----------------
template<bool BT>
__global__ __launch_bounds__(256) void k_gemm64(
    const float* __restrict__ A, int lda,
    const float* __restrict__ B, int ldb,
    int N, int K,
    float* __restrict__ Ppart,
    const float* __restrict__ bias, const float* __restrict__ bias2, int relu,
    float* __restrict__ Cfinal, int ldc) {
  __shared__ __align__(16) float As[64 * 64];
  __shared__ __align__(16) float Bs[64 * 64];
  const float4* As4 = (const float4*)As;
  const float4* Bs4 = (const float4*)Bs;
  int tid = threadIdx.x;
  int cidx = tid & 15;
  int ridx = tid >> 4;
  int n0 = blockIdx.x * 64;
  int splitk = gridDim.y;
  int klen = K / splitk;
  int kbeg = blockIdx.y * klen;
  float acc[4][4] = {};

  for (int k0 = kbeg; k0 < kbeg + klen; k0 += 64) {
#pragma unroll
    for (int i = 0; i < 4; ++i) {
      int f = tid + i * 256;
      int rr = f >> 4, km = f & 15;
      float4 v = *(const float4*)&A[(size_t)rr * lda + k0 + km * 4];
      int c2 = ((rr >> 2) ^ km) & 15, p = rr & 3;
      As[(km * 4 + 0) * 64 + c2 * 4 + p] = v.x;
      As[(km * 4 + 1) * 64 + c2 * 4 + p] = v.y;
      As[(km * 4 + 2) * 64 + c2 * 4 + p] = v.z;
      As[(km * 4 + 3) * 64 + c2 * 4 + p] = v.w;
    }
    if (BT) {
#pragma unroll
      for (int i = 0; i < 4; ++i) {
        int f = tid + i * 256;
        int nn = f >> 4, km = f & 15;
        int gn = n0 + nn;
        float4 v = make_float4(0.f, 0.f, 0.f, 0.f);
        if (gn < N) v = *(const float4*)&B[(size_t)gn * ldb + k0 + km * 4];
        int c2 = ((nn >> 2) ^ km) & 15, p = nn & 3;
        Bs[(km * 4 + 0) * 64 + c2 * 4 + p] = v.x;
        Bs[(km * 4 + 1) * 64 + c2 * 4 + p] = v.y;
        Bs[(km * 4 + 2) * 64 + c2 * 4 + p] = v.z;
        Bs[(km * 4 + 3) * 64 + c2 * 4 + p] = v.w;
      }
    } else {
#pragma unroll
      for (int i = 0; i < 4; ++i) {
        int f = tid + i * 256;
        int kr = f >> 4, nq = f & 15;
        int gn = n0 + nq * 4;
        float4 v = make_float4(0.f, 0.f, 0.f, 0.f);
        if (gn < N) v = *(const float4*)&B[(size_t)(k0 + kr) * ldb + gn];
        ((float4*)Bs)[kr * 16 + ((nq ^ (kr >> 2)) & 15)] = v;
      }
    }
    __syncthreads();
#pragma unroll 8
    for (int kk = 0; kk < 64; ++kk) {
      int sw = kk >> 2;
      float4 a4 = As4[kk * 16 + ((ridx ^ sw) & 15)];
      float4 b4 = Bs4[kk * 16 + ((cidx ^ sw) & 15)];
      float av[4] = {a4.x, a4.y, a4.z, a4.w};
      float bv[4] = {b4.x, b4.y, b4.z, b4.w};
#pragma unroll
      for (int i = 0; i < 4; ++i)
#pragma unroll
        for (int j = 0; j < 4; ++j) acc[i][j] += av[i] * bv[j];
    }
    __syncthreads();
  }

  int gcol = n0 + cidx * 4;
  if (splitk > 1) {
    float* P = Ppart + (size_t)blockIdx.y * 64 * N;
    if (gcol < N) {
#pragma unroll
      for (int i = 0; i < 4; ++i) {
        int row = ridx * 4 + i;
        *(float4*)&P[(size_t)row * N + gcol] =
            make_float4(acc[i][0], acc[i][1], acc[i][2], acc[i][3]);
      }
    }
  } else {
    if (gcol < N) {
      float4 bs = bias ? *(const float4*)&bias[gcol] : make_float4(0, 0, 0, 0);
      if (bias2) {
        float4 b2 = *(const float4*)&bias2[gcol];
        bs.x += b2.x; bs.y += b2.y; bs.z += b2.z; bs.w += b2.w;
      }
#pragma unroll
      for (int i = 0; i < 4; ++i) {
        int row = ridx * 4 + i;
        float4 v = make_float4(acc[i][0] + bs.x, acc[i][1] + bs.y,
                               acc[i][2] + bs.z, acc[i][3] + bs.w);
        if (relu) {
          v.x = fmaxf(v.x, 0.f); v.y = fmaxf(v.y, 0.f);
          v.z = fmaxf(v.z, 0.f); v.w = fmaxf(v.w, 0.f);
        }
        *(float4*)&Cfinal[(size_t)row * ldc + gcol] = v;
      }
    }
  }
}

// ---------------- split-K reduce + bias(+bias2)(+relu), float4 ----------------
__global__ __launch_bounds__(256) void k_reduce4(
    const float* __restrict__ P, int S, int N,
    const float* __restrict__ bias, const float* __restrict__ bias2, int relu,
    float* __restrict__ out, int ldc) {
  int q = blockIdx.x * 256 + threadIdx.x;
  int total = 64 * N / 4;
  if (q >= total) return;
  int e0 = q * 4;
  int row = e0 / N, col = e0 - row * N;
  float4 v = make_float4(0, 0, 0, 0);
  for (int s = 0; s < S; ++s) {
    float4 p = *(const float4*)&P[(size_t)s * 64 * N + e0];
    v.x += p.x; v.y += p.y; v.z += p.z; v.w += p.w;
  }
  if (bias) {
    float4 b = *(const float4*)&bias[col];
    v.x += b.x; v.y += b.y; v.z += b.z; v.w += b.w;
  }
  if (bias2) {
    float4 b = *(const float4*)&bias2[col];
    v.x += b.x; v.y += b.y; v.z += b.z; v.w += b.w;
  }
  if (relu) {
    v.x = fmaxf(v.x, 0.f); v.y = fmaxf(v.y, 0.f);
    v.z = fmaxf(v.z, 0.f); v.w = fmaxf(v.w, 0.f);
  }
  *(float4*)&out[(size_t)row * ldc + col] = v;
}

// ---------------- persistent recurrence, MALL-only sync (relaxed sc1 atomics) ----------------
// 256 blocks x 256 threads, 1 block/CU. Block b: lstm=b>>7, owns h[(b&127)*8 .. +8)
// -> 32 gate rows, whole K in registers (128 floats/thread). Two independent chains.
__global__ __launch_bounds__(256, 1) void k_recur(
    const float* __restrict__ Whh_term, const float* __restrict__ Whh_act,
    const float* __restrict__ xg_term, const float* __restrict__ xg_act,
    float* __restrict__ fin, int* __restrict__ flags) {
  __shared__ float hs[8 * 132];       // 132-pad: p-groups hit disjoint bank quads
  __shared__ float xgs[63 * 32];
  __shared__ float gs[32];
  int b = blockIdx.x, tid = threadIdx.x;
  int lstm = b >> 7, bslot = b & 127, k0 = bslot * 8;
  const float* Whh = lstm ? Whh_act : Whh_term;
  const float* xg  = lstm ? xg_act : xg_term;
  int d = tid >> 3, p = tid & 7;      // d: 32 gate rows, p: K-eighth
  int gate = d >> 3, e = d & 7;
  int row = gate * 1024 + k0 + e;

  // hoist this thread's 128-float weight strip into registers (one-time, 128KB/block)
  float wreg[128];
  {
    const float* wrow = Whh + (size_t)row * 1024 + p * 128;
#pragma unroll
    for (int i = 0; i < 128; i += 4) {
      float4 v = *(const float4*)(wrow + i);
      wreg[i] = v.x; wreg[i + 1] = v.y; wreg[i + 2] = v.z; wreg[i + 3] = v.w;
    }
  }
  // preload this block's xg slice (63 steps x 32 rows) into LDS
  for (int i = tid; i < 63 * 32; i += 256) {
    int t = i >> 5, dd = i & 31;
    xgs[i] = xg[(size_t)t * 4096 + (dd >> 3) * 1024 + k0 + (dd & 7)];
  }
  float c_loc = 0.f;                  // valid for tid<8
  int* myflags = flags + lstm * 128 * 16;

  for (int t = 0; t < 63; ++t) {
    // wait until all 128 producer blocks of this LSTM finished step t (h(t) in fin)
    if (t > 0 && tid < 128) {
      while (__hip_atomic_load(&myflags[tid * 16], __ATOMIC_RELAXED,
                               __HIP_MEMORY_SCOPE_AGENT) < t)
        __builtin_amdgcn_s_sleep(1);
    }
    __syncthreads();
    // stage h(t) (sc1 loads: straight from coherence point, no stale L2)
#pragma unroll
    for (int j = 0; j < 4; ++j) {
      int idx = tid + j * 256;
      float v = __hip_atomic_load(&fin[(size_t)t * 4096 + lstm * 1024 + idx],
                                  __ATOMIC_RELAXED, __HIP_MEMORY_SCOPE_AGENT);
      hs[(idx >> 7) * 132 + (idx & 127)] = v;
    }
    __syncthreads();
    const float* hp = hs + p * 132;
    float sacc[4] = {0.f, 0.f, 0.f, 0.f};
#pragma unroll
    for (int i = 0; i < 128; i += 4) {
      float4 hv = *(const float4*)&hp[i];
      sacc[(i >> 2) & 3] += wreg[i] * hv.x + wreg[i + 1] * hv.y +
                            wreg[i + 2] * hv.z + wreg[i + 3] * hv.w;
    }
    float sum = (sacc[0] + sacc[1]) + (sacc[2] + sacc[3]);
    sum += __shfl_xor(sum, 1);
    sum += __shfl_xor(sum, 2);
    sum += __shfl_xor(sum, 4);
    if (p == 0) gs[d] = sum + xgs[t * 32 + d];
    __syncthreads();
    if (tid < 8) {
      float gi = gs[tid], gf = gs[8 + tid], gg = gs[16 + tid], go = gs[24 + tid];
      float c2 = sigmf(gf) * c_loc + sigmf(gi) * tanhf(gg);
      float h2 = sigmf(go) * tanhf(c2);
      c_loc = c2;
      __hip_atomic_store(&fin[(size_t)(t + 1) * 4096 + lstm * 1024 + k0 + tid], h2,
                         __ATOMIC_RELAXED, __HIP_MEMORY_SCOPE_AGENT);
    }
    if (tid == 0) {
      asm volatile("s_waitcnt vmcnt(0)" ::: "memory");  // wave0's h stores reached MALL
      __hip_atomic_store(&myflags[bslot * 16], t + 1,
                         __ATOMIC_RELAXED, __HIP_MEMORY_SCOPE_AGENT);
    }
  }
}

// ---------------- action logits: [64,30] = ha @ Wa2^T + ba2 ----------------
__global__ __launch_bounds__(256) void k_actlog(
    const float* __restrict__ ha, const float* __restrict__ Wa2,
    const float* __restrict__ ba2, float* __restrict__ out) {
  int t = blockIdx.x, tid = threadIdx.x;
  int v = tid >> 3, p = tid & 7;
  float sum = 0.f;
  if (v < VA) {
    const float* a  = ha + (size_t)t * 1024 + p * 128;
    const float* wr = Wa2 + (size_t)v * 1024 + p * 128;
#pragma unroll 8
    for (int i = 0; i < 128; i += 4) {
      float4 av = *(const float4*)(a + i);
      float4 wv = *(const float4*)(wr + i);
      sum += av.x * wv.x + av.y * wv.y + av.z * wv.z + av.w * wv.w;
    }
  }
  sum += __shfl_xor(sum, 1);
  sum += __shfl_xor(sum, 2);
  sum += __shfl_xor(sum, 4);
  if (p == 0 && v < VA) out[(size_t)t * VA + v] = sum + ba2[v];
}

extern "C" void kernel_launch(void* const* d_in, const int* in_sizes, int n_in,
                              void* d_out, int out_size, void* d_ws, size_t ws_size,
                              hipStream_t stream) {
  const float* memory   = (const float*)d_in[0];
  const int*   actions  = (const int*)d_in[1];
  const int*   words    = (const int*)d_in[2];
  const float* term_Wih = (const float*)d_in[3];
  const float* term_Whh = (const float*)d_in[4];
  const float* term_bih = (const float*)d_in[5];
  const float* term_bhh = (const float*)d_in[6];
  const float* act_Wih  = (const float*)d_in[7];
  const float* act_Whh  = (const float*)d_in[8];
  const float* act_bih  = (const float*)d_in[9];
  const float* act_bhh  = (const float*)d_in[10];
  const float* Wq  = (const float*)d_in[11];
  const float* bq  = (const float*)d_in[12];
  const float* Wa1 = (const float*)d_in[13];
  const float* ba1 = (const float*)d_in[14];
  const float* Wa2 = (const float*)d_in[15];
  const float* ba2 = (const float*)d_in[16];
  const float* Ww1 = (const float*)d_in[17];
  const float* bw1 = (const float*)d_in[18];
  const float* Ww2 = (const float*)d_in[19];
  const float* bw2 = (const float*)d_in[20];
  const float* act_emb  = (const float*)d_in[21];
  const float* word_emb = (const float*)d_in[22];
  float* out = (float*)d_out;

  // workspace layout (floats)
  float* w       = (float*)d_ws;
  float* X_term  = w;                   // 64*1024
  float* X_act   = X_term + 65536;
  float* xg_term = X_act + 65536;       // 64*4096
  float* xg_act  = xg_term + 262144;
  float* fin     = xg_act + 262144;     // 64*4096 [term_h|act_h|stack|ctx]
  float* qbuf    = fin + 262144;        // 64*1024
  float* attn    = qbuf + 65536;        // 64*512
  float* ha      = attn + 32768;        // 64*1024
  float* hw      = ha + 65536;          // 64*1024
  int*   flags   = (int*)(hw + 65536);  // 2*128*16 ints
  float* P       = (float*)(flags + 2 * 128 * 16);

  size_t base_fl = (size_t)(P - w);
  int wsplit = (ws_size >= (base_fl + 2ull * 64 * VW + 1024) * 4) ? 2 : 1;

  k_init<<<65, 256, 0, stream>>>(actions, words, act_emb, word_emb,
                                 X_term, X_act, fin, flags);

  // xg = X @ Wih^T + bih + bhh   (N=4096, K=1024, splitk=4)
  k_gemm64<true><<<dim3(64, 4), 256, 0, stream>>>(X_term, 1024, term_Wih, 1024, 4096, 1024,
                                                  P, nullptr, nullptr, 0, nullptr, 0);
  k_reduce4<<<256, 256, 0, stream>>>(P, 4, 4096, term_bih, term_bhh, 0, xg_term, 4096);
  k_gemm64<true><<<dim3(64, 4), 256, 0, stream>>>(X_act, 1024, act_Wih, 1024, 4096, 1024,
                                                  P, nullptr, nullptr, 0, nullptr, 0);
  k_reduce4<<<256, 256, 0, stream>>>(P, 4, 4096, act_bih, act_bhh, 0, xg_act, 4096);

  // all 63 recurrence steps in one persistent kernel (MALL-sync, reg-resident weights)
  k_recur<<<256, 256, 0, stream>>>(term_Whh, act_Whh, xg_term, xg_act, fin, flags);

  // q = states @ Wq^T + bq   (K=3072, N=1024, splitk=4)
  k_gemm64<true><<<dim3(16, 4), 256, 0, stream>>>(fin, 4096, Wq, 3072, 1024, 3072,
                                                  P, nullptr, nullptr, 0, nullptr, 0);
  k_reduce4<<<64, 256, 0, stream>>>(P, 4, 1024, bq, nullptr, 0, qbuf, 1024);

  // attn = q . memory   (N=512, K=1024, splitk=2)
  k_gemm64<true><<<dim3(8, 2), 256, 0, stream>>>(qbuf, 1024, memory, 1024, 512, 1024,
                                                 P, nullptr, nullptr, 0, nullptr, 0);
  k_reduce4<<<32, 256, 0, stream>>>(P, 2, 512, nullptr, nullptr, 0, attn, 512);

  // ctx = attn @ memory  (N=1024, K=512, splitk=2) -> fin[:,3072:4096]
  k_gemm64<false><<<dim3(16, 2), 256, 0, stream>>>(attn, 512, memory, 1024, 1024, 512,
                                                   P, nullptr, nullptr, 0, nullptr, 0);
  k_reduce4<<<64, 256, 0, stream>>>(P, 2, 1024, nullptr, nullptr, 0, fin + 3072, 4096);

  // ha = relu(final @ Wa1^T + ba1), hw = relu(final @ Ww1^T + bw1)  (K=4096, splitk=8)
  k_gemm64<true><<<dim3(16, 8), 256, 0, stream>>>(fin, 4096, Wa1, 4096, 1024, 4096,
                                                  P, nullptr, nullptr, 0, nullptr, 0);
  k_reduce4<<<64, 256, 0, stream>>>(P, 8, 1024, ba1, nullptr, 1, ha, 1024);
  k_gemm64<true><<<dim3(16, 8), 256, 0, stream>>>(fin, 4096, Ww1, 4096, 1024, 4096,
                                                  P, nullptr, nullptr, 0, nullptr, 0);
  k_reduce4<<<64, 256, 0, stream>>>(P, 8, 1024, bw1, nullptr, 1, hw, 1024);

  // act_logits -> out[0:1920]
  k_actlog<<<64, 256, 0, stream>>>(ha, Wa2, ba2, out);

  // word_logits = hw @ Ww2^T + bw2 -> out[1920:]
  if (wsplit == 2) {
    k_gemm64<true><<<dim3(469, 2), 256, 0, stream>>>(hw, 1024, Ww2, 1024, VW, 1024,
                                                     P, nullptr, nullptr, 0, nullptr, 0);
    k_reduce4<<<1875, 256, 0, stream>>>(P, 2, VW, bw2, nullptr, 0, out + 1920, VW);
  } else {
    k_gemm64<true><<<dim3(469, 1), 256, 0, stream>>>(hw, 1024, Ww2, 1024, VW, 1024,
                                                     nullptr, bw2, nullptr, 0, out + 1920, VW);
  }
}

// Round 4
// 492.326 us; speedup vs baseline: 6.8982x; 1.1707x over previous
//
#include <hip/hip_runtime.h>

#define H 1024
#define T_STEPS 64
#define S_MEM 512
#define VA 30
#define VW 30000

__device__ __forceinline__ float sigmf(float x) { return 1.f / (1.f + expf(-x)); }

// ---------------- init: gather embeddings, stack slices, zero states + htag ----------------
__global__ __launch_bounds__(256) void k_init(
    const int* __restrict__ actions, const int* __restrict__ words,
    const float* __restrict__ act_emb, const float* __restrict__ word_emb,
    float* __restrict__ X_term, float* __restrict__ X_act,
    float* __restrict__ fin, unsigned long long* __restrict__ htag) {
  int b = blockIdx.x, tid = threadIdx.x;
  if (b < T_STEPS) {
    int wi = words[b], ai = actions[b];
    for (int i = tid; i < H; i += 256) {
      float we = word_emb[(size_t)wi * H + i];
      X_term[b * H + i] = we;
      X_act[b * H + i]  = act_emb[(size_t)ai * H + i];
      if (b + 1 < T_STEPS) fin[(size_t)(b + 1) * 4096 + 2048 + i] = we;  // stack_h[t+1]=w_e[t]
    }
    if (b == 0)
      for (int i = tid; i < H; i += 256) fin[2048 + i] = 0.f;            // stack_h[0]=0
  } else if (b == T_STEPS) {
    for (int i = tid; i < H; i += 256) { fin[i] = 0.f; fin[H + i] = 0.f; }
  } else {
    // zero all tag words (64 steps x 2048) so stale tags from a prior replay can't match
    for (int i = (b - 65) * 256 + tid; i < 64 * 2048; i += 64 * 256) htag[i] = 0ull;
  }
}

// ---------------- fp32 GEMM: C[64,N] = A[64,K] * op(B), 64x64 tile, 4x4 micro ----------------
template<bool BT>
__global__ __launch_bounds__(256) void k_gemm64(
    const float* __restrict__ A, int lda,
    const float* __restrict__ B, int ldb,
    int N, int K,
    float* __restrict__ Ppart,
    const float* __restrict__ bias, const float* __restrict__ bias2, int relu,
    float* __restrict__ Cfinal, int ldc) {
  __shared__ __align__(16) float As[64 * 64];
  __shared__ __align__(16) float Bs[64 * 64];
  const float4* As4 = (const float4*)As;
  const float4* Bs4 = (const float4*)Bs;
  int tid = threadIdx.x;
  int cidx = tid & 15;
  int ridx = tid >> 4;
  int n0 = blockIdx.x * 64;
  int splitk = gridDim.y;
  int klen = K / splitk;
  int kbeg = blockIdx.y * klen;
  float acc[4][4] = {};

  for (int k0 = kbeg; k0 < kbeg + klen; k0 += 64) {
#pragma unroll
    for (int i = 0; i < 4; ++i) {
      int f = tid + i * 256;
      int rr = f >> 4, km = f & 15;
      float4 v = *(const float4*)&A[(size_t)rr * lda + k0 + km * 4];
      int c2 = ((rr >> 2) ^ km) & 15, p = rr & 3;
      As[(km * 4 + 0) * 64 + c2 * 4 + p] = v.x;
      As[(km * 4 + 1) * 64 + c2 * 4 + p] = v.y;
      As[(km * 4 + 2) * 64 + c2 * 4 + p] = v.z;
      As[(km * 4 + 3) * 64 + c2 * 4 + p] = v.w;
    }
    if (BT) {
#pragma unroll
      for (int i = 0; i < 4; ++i) {
        int f = tid + i * 256;
        int nn = f >> 4, km = f & 15;
        int gn = n0 + nn;
        float4 v = make_float4(0.f, 0.f, 0.f, 0.f);
        if (gn < N) v = *(const float4*)&B[(size_t)gn * ldb + k0 + km * 4];
        int c2 = ((nn >> 2) ^ km) & 15, p = nn & 3;
        Bs[(km * 4 + 0) * 64 + c2 * 4 + p] = v.x;
        Bs[(km * 4 + 1) * 64 + c2 * 4 + p] = v.y;
        Bs[(km * 4 + 2) * 64 + c2 * 4 + p] = v.z;
        Bs[(km * 4 + 3) * 64 + c2 * 4 + p] = v.w;
      }
    } else {
#pragma unroll
      for (int i = 0; i < 4; ++i) {
        int f = tid + i * 256;
        int kr = f >> 4, nq = f & 15;
        int gn = n0 + nq * 4;
        float4 v = make_float4(0.f, 0.f, 0.f, 0.f);
        if (gn < N) v = *(const float4*)&B[(size_t)(k0 + kr) * ldb + gn];
        ((float4*)Bs)[kr * 16 + ((nq ^ (kr >> 2)) & 15)] = v;
      }
    }
    __syncthreads();
#pragma unroll 8
    for (int kk = 0; kk < 64; ++kk) {
      int sw = kk >> 2;
      float4 a4 = As4[kk * 16 + ((ridx ^ sw) & 15)];
      float4 b4 = Bs4[kk * 16 + ((cidx ^ sw) & 15)];
      float av[4] = {a4.x, a4.y, a4.z, a4.w};
      float bv[4] = {b4.x, b4.y, b4.z, b4.w};
#pragma unroll
      for (int i = 0; i < 4; ++i)
#pragma unroll
        for (int j = 0; j < 4; ++j) acc[i][j] += av[i] * bv[j];
    }
    __syncthreads();
  }

  int gcol = n0 + cidx * 4;
  if (splitk > 1) {
    float* P = Ppart + (size_t)blockIdx.y * 64 * N;
    if (gcol < N) {
#pragma unroll
      for (int i = 0; i < 4; ++i) {
        int row = ridx * 4 + i;
        *(float4*)&P[(size_t)row * N + gcol] =
            make_float4(acc[i][0], acc[i][1], acc[i][2], acc[i][3]);
      }
    }
  } else {
    if (gcol < N) {
      float4 bs = bias ? *(const float4*)&bias[gcol] : make_float4(0, 0, 0, 0);
      if (bias2) {
        float4 b2 = *(const float4*)&bias2[gcol];
        bs.x += b2.x; bs.y += b2.y; bs.z += b2.z; bs.w += b2.w;
      }
#pragma unroll
      for (int i = 0; i < 4; ++i) {
        int row = ridx * 4 + i;
        float4 v = make_float4(acc[i][0] + bs.x, acc[i][1] + bs.y,
                               acc[i][2] + bs.z, acc[i][3] + bs.w);
        if (relu) {
          v.x = fmaxf(v.x, 0.f); v.y = fmaxf(v.y, 0.f);
          v.z = fmaxf(v.z, 0.f); v.w = fmaxf(v.w, 0.f);
        }
        *(float4*)&Cfinal[(size_t)row * ldc + gcol] = v;
      }
    }
  }
}

// ---------------- dual GEMM (BT=true, split-K partials only), z selects (A,B,P) ----------------
__global__ __launch_bounds__(256) void k_gemm_dual(
    const float* __restrict__ A0, const float* __restrict__ A1, int lda,
    const float* __restrict__ B0, const float* __restrict__ B1, int ldb,
    int N, int K, float* __restrict__ P0, float* __restrict__ P1) {
  __shared__ __align__(16) float As[64 * 64];
  __shared__ __align__(16) float Bs[64 * 64];
  const float4* As4 = (const float4*)As;
  const float4* Bs4 = (const float4*)Bs;
  const float* A = blockIdx.z ? A1 : A0;
  const float* B = blockIdx.z ? B1 : B0;
  float* Pp = blockIdx.z ? P1 : P0;
  int tid = threadIdx.x;
  int cidx = tid & 15;
  int ridx = tid >> 4;
  int n0 = blockIdx.x * 64;
  int klen = K / gridDim.y;
  int kbeg = blockIdx.y * klen;
  float acc[4][4] = {};

  for (int k0 = kbeg; k0 < kbeg + klen; k0 += 64) {
#pragma unroll
    for (int i = 0; i < 4; ++i) {
      int f = tid + i * 256;
      int rr = f >> 4, km = f & 15;
      float4 v = *(const float4*)&A[(size_t)rr * lda + k0 + km * 4];
      int c2 = ((rr >> 2) ^ km) & 15, p = rr & 3;
      As[(km * 4 + 0) * 64 + c2 * 4 + p] = v.x;
      As[(km * 4 + 1) * 64 + c2 * 4 + p] = v.y;
      As[(km * 4 + 2) * 64 + c2 * 4 + p] = v.z;
      As[(km * 4 + 3) * 64 + c2 * 4 + p] = v.w;
    }
#pragma unroll
    for (int i = 0; i < 4; ++i) {
      int f = tid + i * 256;
      int nn = f >> 4, km = f & 15;
      int gn = n0 + nn;
      float4 v = make_float4(0.f, 0.f, 0.f, 0.f);
      if (gn < N) v = *(const float4*)&B[(size_t)gn * ldb + k0 + km * 4];
      int c2 = ((nn >> 2) ^ km) & 15, p = nn & 3;
      Bs[(km * 4 + 0) * 64 + c2 * 4 + p] = v.x;
      Bs[(km * 4 + 1) * 64 + c2 * 4 + p] = v.y;
      Bs[(km * 4 + 2) * 64 + c2 * 4 + p] = v.z;
      Bs[(km * 4 + 3) * 64 + c2 * 4 + p] = v.w;
    }
    __syncthreads();
#pragma unroll 8
    for (int kk = 0; kk < 64; ++kk) {
      int sw = kk >> 2;
      float4 a4 = As4[kk * 16 + ((ridx ^ sw) & 15)];
      float4 b4 = Bs4[kk * 16 + ((cidx ^ sw) & 15)];
      float av[4] = {a4.x, a4.y, a4.z, a4.w};
      float bv[4] = {b4.x, b4.y, b4.z, b4.w};
#pragma unroll
      for (int i = 0; i < 4; ++i)
#pragma unroll
        for (int j = 0; j < 4; ++j) acc[i][j] += av[i] * bv[j];
    }
    __syncthreads();
  }
  int gcol = n0 + cidx * 4;
  float* P = Pp + (size_t)blockIdx.y * 64 * N;
  if (gcol < N) {
#pragma unroll
    for (int i = 0; i < 4; ++i) {
      int row = ridx * 4 + i;
      *(float4*)&P[(size_t)row * N + gcol] =
          make_float4(acc[i][0], acc[i][1], acc[i][2], acc[i][3]);
    }
  }
}

// ---------------- split-K reduce + bias(+bias2)(+relu), float4 ----------------
__global__ __launch_bounds__(256) void k_reduce4(
    const float* __restrict__ P, int S, int N,
    const float* __restrict__ bias, const float* __restrict__ bias2, int relu,
    float* __restrict__ out, int ldc) {
  int q = blockIdx.x * 256 + threadIdx.x;
  int total = 64 * N / 4;
  if (q >= total) return;
  int e0 = q * 4;
  int row = e0 / N, col = e0 - row * N;
  float4 v = make_float4(0, 0, 0, 0);
  for (int s = 0; s < S; ++s) {
    float4 p = *(const float4*)&P[(size_t)s * 64 * N + e0];
    v.x += p.x; v.y += p.y; v.z += p.z; v.w += p.w;
  }
  if (bias) {
    float4 b = *(const float4*)&bias[col];
    v.x += b.x; v.y += b.y; v.z += b.z; v.w += b.w;
  }
  if (bias2) {
    float4 b = *(const float4*)&bias2[col];
    v.x += b.x; v.y += b.y; v.z += b.z; v.w += b.w;
  }
  if (relu) {
    v.x = fmaxf(v.x, 0.f); v.y = fmaxf(v.y, 0.f);
    v.z = fmaxf(v.z, 0.f); v.w = fmaxf(v.w, 0.f);
  }
  *(float4*)&out[(size_t)row * ldc + col] = v;
}

// ---------------- dual reduce: blockIdx.y selects (P, bias, bias2, out) ----------------
__global__ __launch_bounds__(256) void k_reduce_dual(
    const float* __restrict__ P0, const float* __restrict__ P1, int S, int N,
    const float* __restrict__ ba0, const float* __restrict__ ba1,
    const float* __restrict__ bb0, const float* __restrict__ bb1,
    float* __restrict__ o0, float* __restrict__ o1, int relu) {
  const float* P = blockIdx.y ? P1 : P0;
  const float* bias = blockIdx.y ? ba1 : ba0;
  const float* bias2 = blockIdx.y ? bb1 : bb0;
  float* out = blockIdx.y ? o1 : o0;
  int q = blockIdx.x * 256 + threadIdx.x;
  int total = 64 * N / 4;
  if (q >= total) return;
  int e0 = q * 4;
  int col = e0 % N;
  float4 v = make_float4(0, 0, 0, 0);
  for (int s = 0; s < S; ++s) {
    float4 p = *(const float4*)&P[(size_t)s * 64 * N + e0];
    v.x += p.x; v.y += p.y; v.z += p.z; v.w += p.w;
  }
  if (bias) {
    float4 b = *(const float4*)&bias[col];
    v.x += b.x; v.y += b.y; v.z += b.z; v.w += b.w;
  }
  if (bias2) {
    float4 b = *(const float4*)&bias2[col];
    v.x += b.x; v.y += b.y; v.z += b.z; v.w += b.w;
  }
  if (relu) {
    v.x = fmaxf(v.x, 0.f); v.y = fmaxf(v.y, 0.f);
    v.z = fmaxf(v.z, 0.f); v.w = fmaxf(v.w, 0.f);
  }
  *(float4*)&out[e0] = v;
}

// ---------------- persistent recurrence v3: tagged-h MALL sync, reg-pinned weights ----------------
// 256 blocks x 256 threads, 1 block/CU. Block b: lstm=b>>7, owns h[(b&127)*8 .. +8).
// Thread (d=tid>>5, p=tid&31): all 4 gate rows of h-elem k0+d, K-chunk [p*32, p*32+32).
__global__ __launch_bounds__(256, 1) void k_recur(
    const float* __restrict__ Whh_term, const float* __restrict__ Whh_act,
    const float* __restrict__ xg_term, const float* __restrict__ xg_act,
    float* __restrict__ fin, unsigned long long* __restrict__ htag) {
  __shared__ float hs[32 * 36];       // [p-chunk][32] pad-36 (4-way max on b128 reads)
  __shared__ float xgs[63 * 32];
  int b = blockIdx.x, tid = threadIdx.x;
  int lstm = b >> 7, k0 = (b & 127) * 8;
  const float* Whh = lstm ? Whh_act : Whh_term;
  const float* xg  = lstm ? xg_act : xg_term;
  int d = tid >> 5, p = tid & 31;

  // weights: 4 gates x 32 K-chunk for h-elem (k0+d); pinned via keep-alive asm
  float wreg[128];
#pragma unroll
  for (int g = 0; g < 4; ++g) {
    const float* wrow = Whh + (size_t)(g * 1024 + k0 + d) * 1024 + p * 32;
#pragma unroll
    for (int i = 0; i < 32; i += 4) {
      float4 v = *(const float4*)(wrow + i);
      wreg[g * 32 + i]     = v.x; wreg[g * 32 + i + 1] = v.y;
      wreg[g * 32 + i + 2] = v.z; wreg[g * 32 + i + 3] = v.w;
    }
  }
#pragma unroll
  for (int i = 0; i < 128; ++i) asm volatile("" : "+v"(wreg[i]));

  // preload xg slice: xgs[t*32 + g*8 + d] = xg[t][g*1024 + k0 + d]
  for (int i = tid; i < 63 * 32; i += 256) {
    int rr = i & 31;
    xgs[i] = xg[(size_t)(i >> 5) * 4096 + (rr >> 3) * 1024 + k0 + (rr & 7)];
  }
  float c_loc = 0.f;

  for (int t = 0; t < 63; ++t) {
    // acquire h(t): poll tagged words (data travels with the tag; 1 MALL round trip)
    if (t > 0) {
      const unsigned long long* src = htag + (size_t)t * 2048 + lstm * 1024;
#pragma unroll
      for (int j = 0; j < 4; ++j) {
        int idx = tid + j * 256;
        unsigned long long v = __hip_atomic_load(&src[idx], __ATOMIC_RELAXED,
                                                 __HIP_MEMORY_SCOPE_AGENT);
        while ((unsigned)(v >> 32) != (unsigned)t) {
          __builtin_amdgcn_s_sleep(1);
          v = __hip_atomic_load(&src[idx], __ATOMIC_RELAXED, __HIP_MEMORY_SCOPE_AGENT);
        }
        hs[(idx >> 5) * 36 + (idx & 31)] = __uint_as_float((unsigned)v);
      }
    } else {
#pragma unroll
      for (int j = 0; j < 4; ++j) {
        int idx = tid + j * 256;
        hs[(idx >> 5) * 36 + (idx & 31)] = 0.f;
      }
    }
    __syncthreads();

    const float* hp = hs + p * 36;
    float s0 = 0.f, s1 = 0.f, s2 = 0.f, s3 = 0.f;
#pragma unroll
    for (int i = 0; i < 32; i += 4) {
      float4 hv = *(const float4*)&hp[i];
      s0 += wreg[i] * hv.x + wreg[i + 1] * hv.y + wreg[i + 2] * hv.z + wreg[i + 3] * hv.w;
      s1 += wreg[32 + i] * hv.x + wreg[33 + i] * hv.y + wreg[34 + i] * hv.z + wreg[35 + i] * hv.w;
      s2 += wreg[64 + i] * hv.x + wreg[65 + i] * hv.y + wreg[66 + i] * hv.z + wreg[67 + i] * hv.w;
      s3 += wreg[96 + i] * hv.x + wreg[97 + i] * hv.y + wreg[98 + i] * hv.z + wreg[99 + i] * hv.w;
    }
#pragma unroll
    for (int m = 1; m <= 16; m <<= 1) {
      s0 += __shfl_xor(s0, m); s1 += __shfl_xor(s1, m);
      s2 += __shfl_xor(s2, m); s3 += __shfl_xor(s3, m);
    }
    if (p == 0) {
      float gi = s0 + xgs[t * 32 + d];
      float gf = s1 + xgs[t * 32 + 8 + d];
      float gg = s2 + xgs[t * 32 + 16 + d];
      float go = s3 + xgs[t * 32 + 24 + d];
      float c2 = sigmf(gf) * c_loc + sigmf(gi) * tanhf(gg);
      float h2 = sigmf(go) * tanhf(c2);
      c_loc = c2;
      fin[(size_t)(t + 1) * 4096 + lstm * 1024 + k0 + d] = h2;  // plain (for tail kernels)
      __hip_atomic_store(&htag[(size_t)(t + 1) * 2048 + lstm * 1024 + k0 + d],
                         (((unsigned long long)(t + 1)) << 32) |
                             (unsigned long long)__float_as_uint(h2),
                         __ATOMIC_RELAXED, __HIP_MEMORY_SCOPE_AGENT);
    }
    __syncthreads();   // protect hs reuse next iteration
  }
}

// ---------------- action logits: [64,30] = ha @ Wa2^T + ba2 ----------------
__global__ __launch_bounds__(256) void k_actlog(
    const float* __restrict__ ha, const float* __restrict__ Wa2,
    const float* __restrict__ ba2, float* __restrict__ out) {
  int t = blockIdx.x, tid = threadIdx.x;
  int v = tid >> 3, p = tid & 7;
  float sum = 0.f;
  if (v < VA) {
    const float* a  = ha + (size_t)t * 1024 + p * 128;
    const float* wr = Wa2 + (size_t)v * 1024 + p * 128;
#pragma unroll 8
    for (int i = 0; i < 128; i += 4) {
      float4 av = *(const float4*)(a + i);
      float4 wv = *(const float4*)(wr + i);
      sum += av.x * wv.x + av.y * wv.y + av.z * wv.z + av.w * wv.w;
    }
  }
  sum += __shfl_xor(sum, 1);
  sum += __shfl_xor(sum, 2);
  sum += __shfl_xor(sum, 4);
  if (p == 0 && v < VA) out[(size_t)t * VA + v] = sum + ba2[v];
}

extern "C" void kernel_launch(void* const* d_in, const int* in_sizes, int n_in,
                              void* d_out, int out_size, void* d_ws, size_t ws_size,
                              hipStream_t stream) {
  const float* memory   = (const float*)d_in[0];
  const int*   actions  = (const int*)d_in[1];
  const int*   words    = (const int*)d_in[2];
  const float* term_Wih = (const float*)d_in[3];
  const float* term_Whh = (const float*)d_in[4];
  const float* term_bih = (const float*)d_in[5];
  const float* term_bhh = (const float*)d_in[6];
  const float* act_Wih  = (const float*)d_in[7];
  const float* act_Whh  = (const float*)d_in[8];
  const float* act_bih  = (const float*)d_in[9];
  const float* act_bhh  = (const float*)d_in[10];
  const float* Wq  = (const float*)d_in[11];
  const float* bq  = (const float*)d_in[12];
  const float* Wa1 = (const float*)d_in[13];
  const float* ba1 = (const float*)d_in[14];
  const float* Wa2 = (const float*)d_in[15];
  const float* ba2 = (const float*)d_in[16];
  const float* Ww1 = (const float*)d_in[17];
  const float* bw1 = (const float*)d_in[18];
  const float* Ww2 = (const float*)d_in[19];
  const float* bw2 = (const float*)d_in[20];
  const float* act_emb  = (const float*)d_in[21];
  const float* word_emb = (const float*)d_in[22];
  float* out = (float*)d_out;

  // workspace layout (floats)
  float* w       = (float*)d_ws;
  float* X_term  = w;                   // 64*1024
  float* X_act   = X_term + 65536;
  float* xg_term = X_act + 65536;       // 64*4096
  float* xg_act  = xg_term + 262144;
  float* fin     = xg_act + 262144;     // 64*4096 [term_h|act_h|stack|ctx]
  float* qbuf    = fin + 262144;        // 64*1024
  float* attn    = qbuf + 65536;        // 64*512
  float* ha      = attn + 32768;        // 64*1024
  float* hw      = ha + 65536;          // 64*1024
  unsigned long long* htag = (unsigned long long*)(hw + 65536);  // 64*2048 u64
  float* P       = (float*)(htag + 64 * 2048);

  size_t base_fl = (size_t)(P - w);
  int wsplit = (ws_size >= (base_fl + 2ull * 64 * VW + 1024) * 4) ? 2 : 1;

  k_init<<<129, 256, 0, stream>>>(actions, words, act_emb, word_emb,
                                  X_term, X_act, fin, htag);

  // xg pair: xg = X @ Wih^T + bih + bhh   (N=4096, K=1024, splitk=2, z=2)
  k_gemm_dual<<<dim3(64, 2, 2), 256, 0, stream>>>(
      X_term, X_act, 1024, term_Wih, act_Wih, 1024, 4096, 1024, P, P + 524288);
  k_reduce_dual<<<dim3(256, 2), 256, 0, stream>>>(
      P, P + 524288, 2, 4096, term_bih, act_bih, term_bhh, act_bhh, xg_term, xg_act, 0);

  // all 63 recurrence steps, tagged-h MALL sync
  k_recur<<<256, 256, 0, stream>>>(term_Whh, act_Whh, xg_term, xg_act, fin, htag);

  // q = states @ Wq^T + bq   (K=3072, N=1024, splitk=8)
  k_gemm64<true><<<dim3(16, 8), 256, 0, stream>>>(fin, 4096, Wq, 3072, 1024, 3072,
                                                  P, nullptr, nullptr, 0, nullptr, 0);
  k_reduce4<<<64, 256, 0, stream>>>(P, 8, 1024, bq, nullptr, 0, qbuf, 1024);

  // attn = q . memory   (N=512, K=1024, splitk=8)
  k_gemm64<true><<<dim3(8, 8), 256, 0, stream>>>(qbuf, 1024, memory, 1024, 512, 1024,
                                                 P, nullptr, nullptr, 0, nullptr, 0);
  k_reduce4<<<32, 256, 0, stream>>>(P, 8, 512, nullptr, nullptr, 0, attn, 512);

  // ctx = attn @ memory  (N=1024, K=512, splitk=8) -> fin[:,3072:4096]
  k_gemm64<false><<<dim3(16, 8), 256, 0, stream>>>(attn, 512, memory, 1024, 1024, 512,
                                                   P, nullptr, nullptr, 0, nullptr, 0);
  k_reduce4<<<64, 256, 0, stream>>>(P, 8, 1024, nullptr, nullptr, 0, fin + 3072, 4096);

  // ha/hw pair: relu(final @ W^T + b)   (N=1024, K=4096, splitk=8, z=2)
  k_gemm_dual<<<dim3(16, 8, 2), 256, 0, stream>>>(
      fin, fin, 4096, Wa1, Ww1, 4096, 1024, 4096, P, P + 524288);
  k_reduce_dual<<<dim3(64, 2), 256, 0, stream>>>(
      P, P + 524288, 8, 1024, ba1, bw1, nullptr, nullptr, ha, hw, 1);

  // act_logits -> out[0:1920]
  k_actlog<<<64, 256, 0, stream>>>(ha, Wa2, ba2, out);

  // word_logits = hw @ Ww2^T + bw2 -> out[1920:]
  if (wsplit == 2) {
    k_gemm64<true><<<dim3(469, 2), 256, 0, stream>>>(hw, 1024, Ww2, 1024, VW, 1024,
                                                     P, nullptr, nullptr, 0, nullptr, 0);
    k_reduce4<<<1875, 256, 0, stream>>>(P, 2, VW, bw2, nullptr, 0, out + 1920, VW);
  } else {
    k_gemm64<true><<<dim3(469, 1), 256, 0, stream>>>(hw, 1024, Ww2, 1024, VW, 1024,
                                                     nullptr, bw2, nullptr, 0, out + 1920, VW);
  }
}